// Round 7
// baseline (305.791 us; speedup 1.0000x reference)
//
#include <hip/hip_runtime.h>
#include <cstdint>

// ---------------------------------------------------------------------------
// AttentionAIC: dual-stream QKV proj + per-head RMSNorm + joint SDPA + out-proj
// B=1, S=2048, S_enc=256, D=1536, H=24, HD=64, T=2304.
// Context output discarded -> skip add_q_proj, encoder q-rows, to_add_out.
// R7: (a) flash P stored transposed [t][q] rows padded to 20 shorts:
//     16 b16 writes -> 2 b64 writes per g (A-frag becomes 8 strided u16
//     reads); LDS-pipe per unit 153 -> ~106 cyc. Incremental staging ptrs.
// (b) out-proj split-K x2 (384 blocks vs 192 = 0.75/CU) + float4 add kernel.
// ---------------------------------------------------------------------------

typedef __attribute__((ext_vector_type(8))) short s16x8;   // 8 x bf16
typedef __attribute__((ext_vector_type(4))) float f32x4;

#define LOG2E 1.4426950408889634f

__device__ __forceinline__ short f2bf(float f) {          // RNE (epilogues)
  union { float f; uint32_t u; } v; v.f = f;
  uint32_t r = v.u + 0x7FFFu + ((v.u >> 16) & 1u);
  return (short)(r >> 16);
}
__device__ __forceinline__ short f2bf_fast(float f) {     // round-to-nearest
  union { float f; uint32_t u; } v; v.f = f;
  return (short)((v.u + 0x8000u) >> 16);
}

typedef uint32_t __attribute__((address_space(1)))* gas_u32;
typedef uint32_t __attribute__((address_space(3)))* las_u32;

// async global->LDS, 16B per lane; dest must be wave-uniform base + lane*16
__device__ __forceinline__ void gload_lds16(const short* g, short* l) {
  __builtin_amdgcn_global_load_lds((gas_u32)(g), (las_u32)(l), 16, 0, 0);
}

// ---------------------------------------------------------------------------
// fp32 -> bf16 conversion (8 segments in one launch)
// ---------------------------------------------------------------------------
struct CvtSeg { const float* src; short* dst; int n4; };
struct CvtArgs { CvtSeg s[8]; };

__global__ __launch_bounds__(256) void cvt_bf16_kernel(CvtArgs a) {
  const int stride = gridDim.x * blockDim.x;
  const int tid = blockIdx.x * blockDim.x + threadIdx.x;
  for (int i = 0; i < 8; ++i) {
    const float4* src = (const float4*)a.s[i].src;
    short* dst = a.s[i].dst;
    const int n4 = a.s[i].n4;
    for (int j = tid; j < n4; j += stride) {
      float4 v = src[j];
      short4 o;
      o.x = f2bf(v.x); o.y = f2bf(v.y); o.z = f2bf(v.z); o.w = f2bf(v.w);
      *(short4*)(dst + (size_t)j * 4) = o;
    }
  }
}

// out[j] += part[j], float4
__global__ __launch_bounds__(256) void add_kernel(float* __restrict__ out,
                                                  const float* __restrict__ part,
                                                  int n4) {
  const int stride = gridDim.x * blockDim.x;
  for (int j = blockIdx.x * blockDim.x + threadIdx.x; j < n4; j += stride) {
    float4 a = ((const float4*)out)[j];
    float4 b = ((const float4*)part)[j];
    a.x += b.x; a.y += b.y; a.z += b.z; a.w += b.w;
    ((float4*)out)[j] = a;
  }
}

// ---------------------------------------------------------------------------
// GEMM (R4-proven): C[M,1536] = A[M,1536] @ W[1536,1536]^T (+bias), fused
// epilogues. 128x128 tile, BK=32, 4 waves (2x2), wave = 64x64 via 4x4 MFMA.
// kbeg/kend enable split-K (OUT mode only; partials summed by add_kernel).
// ---------------------------------------------------------------------------
enum { MODE_Q = 0, MODE_K = 1, MODE_V = 2, MODE_OUT = 3 };

struct GemmCfg {
  const short* A;      // [M,1536] bf16
  const short* W;      // [1536,1536] bf16, row-major [N][K]
  const float* bias;   // [1536] fp32 (nullptr -> 0)
  const float* normw;  // [64] fp32 (Q/K modes)
  void* dst;
  int toff;            // t offset for K/V (0 hidden, 2048 encoder)
  int mode;
  int mtiles;          // # of 128-row M tiles (16 hidden, 2 encoder)
  int kbeg, kend;      // K range (split-K for OUT mode)
};
struct GemmArgs { GemmCfg c[5]; };

__global__ __launch_bounds__(256) void proj_gemm_kernel(GemmArgs args) {
  const GemmCfg cfg = args.c[blockIdx.z];
  if ((int)blockIdx.y >= cfg.mtiles) return;
  constexpr int K = 1536;
  __shared__ short As[4096];  // [128][32]
  __shared__ short Bs[4096];  // [128][32]
  const int t = threadIdx.x;
  const int lane = t & 63;
  const int wave = t >> 6;
  const int l16 = lane & 15;
  const int quad = lane >> 4;
  const int wm = wave >> 1;
  const int wn = wave & 1;

  const short* __restrict__ Ag = cfg.A + (size_t)(blockIdx.y * 128) * K;
  const short* __restrict__ Wg = cfg.W + (size_t)(blockIdx.x * 128) * K;
  const int srow = t >> 2;          // 0..63
  const int scol = (t & 3) << 3;    // 0,8,16,24

  const f32x4 z4 = {0.f, 0.f, 0.f, 0.f};
  f32x4 acc[4][4];
#pragma unroll
  for (int i = 0; i < 4; ++i) {
#pragma unroll
    for (int j = 0; j < 4; ++j) acc[i][j] = z4;
  }

  for (int k0 = cfg.kbeg; k0 < cfg.kend; k0 += 32) {
    gload_lds16(Ag + (size_t)srow * K + k0 + scol, As + t * 8);
    gload_lds16(Ag + (size_t)(srow + 64) * K + k0 + scol, As + 2048 + t * 8);
    gload_lds16(Wg + (size_t)srow * K + k0 + scol, Bs + t * 8);
    gload_lds16(Wg + (size_t)(srow + 64) * K + k0 + scol, Bs + 2048 + t * 8);
    __syncthreads();
    s16x8 af[4], bfr[4];
#pragma unroll
    for (int i = 0; i < 4; ++i)
      af[i] = *(const s16x8*)(As + (wm * 64 + i * 16 + l16) * 32 + quad * 8);
#pragma unroll
    for (int i = 0; i < 4; ++i)
      bfr[i] = *(const s16x8*)(Bs + (wn * 64 + i * 16 + l16) * 32 + quad * 8);
#pragma unroll
    for (int mi = 0; mi < 4; ++mi) {
#pragma unroll
      for (int ni = 0; ni < 4; ++ni)
        acc[mi][ni] = __builtin_amdgcn_mfma_f32_16x16x32_bf16(af[mi], bfr[ni], acc[mi][ni], 0, 0, 0);
    }
    __syncthreads();
  }

  // epilogue: C/D layout col=lane&15, row=quad*4+reg
  const int nbase = blockIdx.x * 128 + wn * 64;   // 64-aligned -> one head/wave
  const int mbase = blockIdx.y * 128 + wm * 64;
  const int mode = cfg.mode;
  const int h = nbase >> 6;

  float biasv[4], nwv[4];
#pragma unroll
  for (int ni = 0; ni < 4; ++ni) {
    int col = nbase + ni * 16 + l16;
    biasv[ni] = cfg.bias ? cfg.bias[col] : 0.f;
    nwv[ni] = (mode == MODE_Q || mode == MODE_K) ? cfg.normw[col & 63] : 0.f;
  }

#pragma unroll
  for (int mi = 0; mi < 4; ++mi) {
    float vv[4][4];
#pragma unroll
    for (int ni = 0; ni < 4; ++ni) {
#pragma unroll
      for (int r = 0; r < 4; ++r) vv[ni][r] = acc[mi][ni][r] + biasv[ni];
    }
    if (mode == MODE_Q || mode == MODE_K) {
      float ss[4];
#pragma unroll
      for (int r = 0; r < 4; ++r)
        ss[r] = vv[0][r] * vv[0][r] + vv[1][r] * vv[1][r] +
                vv[2][r] * vv[2][r] + vv[3][r] * vv[3][r];
#pragma unroll
      for (int r = 0; r < 4; ++r) {
        ss[r] += __shfl_xor(ss[r], 1);
        ss[r] += __shfl_xor(ss[r], 2);
        ss[r] += __shfl_xor(ss[r], 4);
        ss[r] += __shfl_xor(ss[r], 8);
        float rs = rsqrtf(ss[r] * (1.0f / 64.0f) + 1e-6f);
#pragma unroll
        for (int ni = 0; ni < 4; ++ni) vv[ni][r] *= rs * nwv[ni];
      }
    }
    const int row0 = mbase + mi * 16 + quad * 4;  // + r
    if (mode == MODE_Q) {
      short* Qd = (short*)cfg.dst;  // [24][2048][64]
#pragma unroll
      for (int ni = 0; ni < 4; ++ni) {
        int d = ni * 16 + l16;
#pragma unroll
        for (int r = 0; r < 4; ++r)
          Qd[((size_t)h * 2048 + row0 + r) * 64 + d] = f2bf(vv[ni][r]);
      }
    } else if (mode == MODE_K) {
      short* Kd = (short*)cfg.dst;  // [24][2304][64]
#pragma unroll
      for (int ni = 0; ni < 4; ++ni) {
        int d = ni * 16 + l16;
#pragma unroll
        for (int r = 0; r < 4; ++r)
          Kd[((size_t)h * 2304 + cfg.toff + row0 + r) * 64 + d] = f2bf(vv[ni][r]);
      }
    } else if (mode == MODE_V) {
      short* Vd = (short*)cfg.dst;  // V^T: [24][64][2304]
#pragma unroll
      for (int ni = 0; ni < 4; ++ni) {
        int d = ni * 16 + l16;
        short4 o4;
        o4.x = f2bf(vv[ni][0]); o4.y = f2bf(vv[ni][1]);
        o4.z = f2bf(vv[ni][2]); o4.w = f2bf(vv[ni][3]);
        *(short4*)(Vd + ((size_t)h * 64 + d) * 2304 + cfg.toff + row0) = o4;
      }
    } else {  // MODE_OUT: fp32 row-major [2048][1536]
      float* Od = (float*)cfg.dst;
#pragma unroll
      for (int ni = 0; ni < 4; ++ni) {
        int col = nbase + ni * 16 + l16;
#pragma unroll
        for (int r = 0; r < 4; ++r)
          Od[(size_t)(row0 + r) * 1536 + col] = vv[ni][r];
      }
    }
  }
}

// ---------------------------------------------------------------------------
// Flash attention v6: block = (64 q-rows, head). Wave w: qw=w&1 owns 32
// q-rows (two 16-row groups), ks=w>>1 owns a 1152-k stream (36 x 32-t tiles).
// Each pair (same ks) double-buffers a 32x64 K tile + 64x32 V^T tile via
// global_load_lds (source XOR-chunk swizzled); K/V MFMA fragments read ONCE
// per iter and reused by both q-groups. P stored TRANSPOSED [t=32][q=16]
// rows padded to 20 shorts: 4 rr values contiguous -> 2 ds_write_b64 per g
// (was 16 b16); A-frag = 8 strided ds_read_u16 (~2-way banks). No online max
// (|s|<=8, RMSNormed q,k); l = P @ ones. Cross-stream combine via LDS.
// Grid 768 = 8 XCD * 3 heads * 32 qblk. LDS 43008 B -> 3 blocks/CU.
// ---------------------------------------------------------------------------
__global__ __launch_bounds__(256) void flash_kernel(
    const short* __restrict__ Q, const short* __restrict__ Kc,
    const short* __restrict__ VT, const float* __restrict__ mask,
    short* __restrict__ AO) {
  const int b = blockIdx.x;
  const int h = (b & 7) * 3 + ((b >> 3) % 3);
  const int q0 = ((b >> 3) / 3) * 64;
  const int lane = threadIdx.x & 63;
  const int wave = threadIdx.x >> 6;
  const int qw = wave & 1;   // which 32-row q half
  const int ks = wave >> 1;  // k stream
  const int l16 = lane & 15;
  const int quad = lane >> 4;

  // shorts: Kt (ks*2+buf)*2048 @0 ; Vt @8192 ; P @16384: (wave*2+g)*640
  __shared__ __align__(16) short smem[21504];   // 43008 B

  const short* Kh = Kc + (size_t)h * 2304 * 64;
  const short* Vh = VT + (size_t)h * 64 * 2304;

  // Q fragments for this wave's two 16-row groups
  s16x8 aq0[2], aq1[2];
#pragma unroll
  for (int g = 0; g < 2; ++g) {
    const short* Qrow =
        Q + ((size_t)h * 2048 + q0 + qw * 32 + g * 16 + l16) * 64;
    aq0[g] = *(const s16x8*)(Qrow + quad * 8);
    aq1[g] = *(const s16x8*)(Qrow + quad * 8 + 32);
  }

  s16x8 ones;
#pragma unroll
  for (int i = 0; i < 8; ++i) ones[i] = (short)0x3F80;  // bf16 1.0

  const f32x4 z4 = {0.f, 0.f, 0.f, 0.f};
  f32x4 o[2][4];
#pragma unroll
  for (int g = 0; g < 2; ++g)
#pragma unroll
    for (int ni = 0; ni < 4; ++ni) o[g][ni] = z4;
  f32x4 lacc[2] = {z4, z4};
  const float SC = 0.125f * LOG2E;
  const int kbase = ks * 1152;

  // incremental staging pointers (two row-halves c=0,1 per tile)
  const short* kgp[2];
  const short* vgp[2];
#pragma unroll
  for (int c = 0; c < 2; ++c) {
    const int gi = c * 128 + qw * 64 + lane;
    const int trow = gi >> 3, cp = gi & 7;
    kgp[c] = Kh + (size_t)(kbase + trow) * 64 + ((cp ^ (trow & 7)) << 3);
    const int d = gi >> 2, cpv = gi & 3;
    vgp[c] = Vh + (size_t)d * 2304 + kbase + ((cpv ^ ((d >> 1) & 3)) << 3);
  }
  short* ktb[2] = {smem + (ks * 2) * 2048, smem + (ks * 2 + 1) * 2048};
  short* vtb[2] = {smem + 8192 + (ks * 2) * 2048, smem + 8192 + (ks * 2 + 1) * 2048};

  auto stage = [&](int buf) {
#pragma unroll
    for (int c = 0; c < 2; ++c) {
      gload_lds16(kgp[c], ktb[buf] + c * 1024 + qw * 512 + lane * 8);
      gload_lds16(vgp[c], vtb[buf] + c * 1024 + qw * 512 + lane * 8);
      kgp[c] += 32 * 64;
      vgp[c] += 32;
    }
  };

  stage(0);
  __syncthreads();

  short* Pg0 = smem + 16384 + (wave * 2) * 640;   // [t=32][20], g=0
  short* Pg1 = Pg0 + 640;                         // g=1

  for (int it = 0; it < 36; ++it) {
    const int buf = it & 1;
    if (it < 35) stage(buf ^ 1);
    const short* kt = ktb[buf];
    const short* vt = vtb[buf];
    const int kb = kbase + it * 32;

    // K/V fragments: read ONCE, reused by both q-groups
    s16x8 bk[2][2];
#pragma unroll
    for (int ni = 0; ni < 2; ++ni) {
      const int tt = ni * 16 + l16;
      const short* kr = kt + tt * 64;
      bk[ni][0] = *(const s16x8*)(kr + ((quad ^ (tt & 7)) << 3));
      bk[ni][1] = *(const s16x8*)(kr + (((quad + 4) ^ (tt & 7)) << 3));
    }
    s16x8 bv[4];
#pragma unroll
    for (int ni = 0; ni < 4; ++ni) {
      const int d = ni * 16 + l16;
      bv[ni] = *(const s16x8*)(vt + d * 32 + ((quad ^ ((d >> 1) & 3)) << 3));
    }
    float mvl[2];
#pragma unroll
    for (int ni = 0; ni < 2; ++ni) mvl[ni] = mask[kb + ni * 16 + l16] * LOG2E;

#pragma unroll
    for (int g = 0; g < 2; ++g) {
      short* Pg = g ? Pg1 : Pg0;
      // QK^T -> exp -> P^T[t][q] (rows padded to 20; 1 b64 write per ni)
#pragma unroll
      for (int ni = 0; ni < 2; ++ni) {
        f32x4 s = __builtin_amdgcn_mfma_f32_16x16x32_bf16(aq0[g], bk[ni][0], z4, 0, 0, 0);
        s = __builtin_amdgcn_mfma_f32_16x16x32_bf16(aq1[g], bk[ni][1], s, 0, 0, 0);
        short4 pk;
        pk.x = f2bf_fast(__builtin_amdgcn_exp2f(fmaf(s[0], SC, mvl[ni])));
        pk.y = f2bf_fast(__builtin_amdgcn_exp2f(fmaf(s[1], SC, mvl[ni])));
        pk.z = f2bf_fast(__builtin_amdgcn_exp2f(fmaf(s[2], SC, mvl[ni])));
        pk.w = f2bf_fast(__builtin_amdgcn_exp2f(fmaf(s[3], SC, mvl[ni])));
        *(short4*)(Pg + (ni * 16 + l16) * 20 + quad * 4) = pk;
      }
      // A-frag: ap[j] = P[q=l16][t=quad*8+j]  (8 strided u16 reads)
      const short* pb = Pg + quad * 160 + l16;
      union { s16x8 v; short e[8]; } ap;
#pragma unroll
      for (int j = 0; j < 8; ++j) ap.e[j] = pb[j * 20];
      lacc[g] = __builtin_amdgcn_mfma_f32_16x16x32_bf16(ap.v, ones, lacc[g], 0, 0, 0);
#pragma unroll
      for (int ni = 0; ni < 4; ++ni)
        o[g][ni] = __builtin_amdgcn_mfma_f32_16x16x32_bf16(ap.v, bv[ni], o[g][ni], 0, 0, 0);
    }
    __syncthreads();   // next tile's staging landed during compute
  }

  // cross-stream combine: ks=1 dumps (o,l) to LDS (reuses K/V region), ks=0 sums
  f32x4* R = (f32x4*)smem;   // [qw*64+lane][10]
  if (ks == 1) {
    f32x4* Rw = R + (qw * 64 + lane) * 10;
#pragma unroll
    for (int g = 0; g < 2; ++g) {
#pragma unroll
      for (int ni = 0; ni < 4; ++ni) Rw[g * 5 + ni] = o[g][ni];
      Rw[g * 5 + 4] = lacc[g];
    }
  }
  __syncthreads();
  if (ks == 0) {
    const f32x4* Rw = R + (qw * 64 + lane) * 10;
#pragma unroll
    for (int g = 0; g < 2; ++g) {
#pragma unroll
      for (int ni = 0; ni < 4; ++ni) o[g][ni] += Rw[g * 5 + ni];
      f32x4 ls = lacc[g] + Rw[g * 5 + 4];
#pragma unroll
      for (int rr = 0; rr < 4; ++rr) {
        float inv = 1.0f / ls[rr];
        int tq = q0 + qw * 32 + g * 16 + quad * 4 + rr;
#pragma unroll
        for (int ni = 0; ni < 4; ++ni)
          AO[(size_t)tq * 1536 + h * 64 + ni * 16 + l16] = f2bf(o[g][ni][rr] * inv);
      }
    }
  }
}

// ---------------------------------------------------------------------------
extern "C" void kernel_launch(void* const* d_in, const int* in_sizes, int n_in,
                              void* d_out, int out_size, void* d_ws, size_t ws_size,
                              hipStream_t stream) {
  (void)in_sizes; (void)n_in; (void)out_size; (void)ws_size;
  const float* hidden = (const float*)d_in[0];
  const float* enc    = (const float*)d_in[1];
  const float* amask  = (const float*)d_in[2];
  const float* wq  = (const float*)d_in[3];  const float* bq  = (const float*)d_in[4];
  const float* wk  = (const float*)d_in[5];  const float* bk  = (const float*)d_in[6];
  const float* wv  = (const float*)d_in[7];  const float* bv  = (const float*)d_in[8];
  const float* nqw = (const float*)d_in[9];  const float* nkw = (const float*)d_in[10];
  // d_in[11],[12],[17]: add_q_proj + norm_added_q -> dead (context q unused)
  const float* wak = (const float*)d_in[13]; const float* bak = (const float*)d_in[14];
  const float* wav = (const float*)d_in[15]; const float* bav = (const float*)d_in[16];
  const float* nakw = (const float*)d_in[18];
  const float* wo  = (const float*)d_in[19]; const float* bo  = (const float*)d_in[20];
  // d_in[21],[22]: to_add_out -> dead
  float* out = (float*)d_out;

  char* p = (char*)d_ws;
  auto carve = [&](size_t bytes) { char* r = p; p += (bytes + 255) & ~(size_t)255; return r; };
  short* Xb   = (short*)carve((size_t)2048 * 1536 * 2);
  short* Eb   = (short*)carve((size_t)256 * 1536 * 2);
  short* Wqb  = (short*)carve((size_t)1536 * 1536 * 2);
  short* Wkb  = (short*)carve((size_t)1536 * 1536 * 2);
  short* Wvb  = (short*)carve((size_t)1536 * 1536 * 2);
  short* Wakb = (short*)carve((size_t)1536 * 1536 * 2);
  short* Wavb = (short*)carve((size_t)1536 * 1536 * 2);
  short* Wob  = (short*)carve((size_t)1536 * 1536 * 2);
  short* Qb   = (short*)carve((size_t)24 * 2048 * 64 * 2);
  short* Kb   = (short*)carve((size_t)24 * 2304 * 64 * 2);
  short* VTb  = (short*)carve((size_t)24 * 64 * 2304 * 2);
  short* AOb  = (short*)carve((size_t)2048 * 1536 * 2);
  float* Pbuf = (float*)carve((size_t)2048 * 1536 * 4);

  CvtArgs ca;
  ca.s[0] = {hidden, Xb, 2048 * 1536 / 4};
  ca.s[1] = {enc,    Eb, 256 * 1536 / 4};
  ca.s[2] = {wq,  Wqb,  1536 * 1536 / 4};
  ca.s[3] = {wk,  Wkb,  1536 * 1536 / 4};
  ca.s[4] = {wv,  Wvb,  1536 * 1536 / 4};
  ca.s[5] = {wak, Wakb, 1536 * 1536 / 4};
  ca.s[6] = {wav, Wavb, 1536 * 1536 / 4};
  ca.s[7] = {wo,  Wob,  1536 * 1536 / 4};
  cvt_bf16_kernel<<<dim3(1024), dim3(256), 0, stream>>>(ca);

  GemmArgs g1;  // all five projections in one launch (z = 0..4)
  g1.c[0] = {Xb, Wqb,  bq,  nqw,     (void*)Qb,  0,    MODE_Q, 16, 0, 1536};
  g1.c[1] = {Xb, Wkb,  bk,  nkw,     (void*)Kb,  0,    MODE_K, 16, 0, 1536};
  g1.c[2] = {Xb, Wvb,  bv,  nullptr, (void*)VTb, 0,    MODE_V, 16, 0, 1536};
  g1.c[3] = {Eb, Wakb, bak, nakw,    (void*)Kb,  2048, MODE_K, 2,  0, 1536};
  g1.c[4] = {Eb, Wavb, bav, nullptr, (void*)VTb, 2048, MODE_V, 2,  0, 1536};
  proj_gemm_kernel<<<dim3(12, 16, 5), dim3(256), 0, stream>>>(g1);

  flash_kernel<<<dim3(768), dim3(256), 0, stream>>>(Qb, Kb, VTb, amask, AOb);

  GemmArgs g3;  // out projection, split-K x2 -> out (k<768, +bias) / Pbuf
  g3.c[0] = {AOb, Wob, bo,      nullptr, (void*)out,  0, MODE_OUT, 16, 0,   768};
  g3.c[1] = {AOb, Wob, nullptr, nullptr, (void*)Pbuf, 0, MODE_OUT, 16, 768, 1536};
  proj_gemm_kernel<<<dim3(12, 16, 2), dim3(256), 0, stream>>>(g3);
  add_kernel<<<dim3(1024), dim3(256), 0, stream>>>(out, Pbuf, 2048 * 1536 / 4);
}